// Round 1
// baseline (369.865 us; speedup 1.0000x reference)
//
#include <hip/hip_runtime.h>

// BranchNet fused pipeline (2 kernels):
//   k_prep: Wcomb = Wb@We.T (fp64), bcomb; Wfold[b] = Wb@Wc[b] (bf16 [b][c][k]); bfold.
//   k_main: per 64-row block: stage x fp32->LDS (single x read) -> fp64 routing with
//           Wcomb in VGPRs (x broadcast from LDS) -> in-LDS branch buckets ->
//           per-branch 16x16x32 bf16 MFMA tiles -> direct stores.
// Sizes: N=131072, IN=256, HID=256, B=8, C=128.

#define NROWS 131072
#define ROWS  64
#define XST   260   // xs row stride (floats): %4==0 keeps 16B alignment, %32==4 rotates bank quads

typedef __bf16 bf16x8 __attribute__((ext_vector_type(8)));
typedef float  f32x4  __attribute__((ext_vector_type(4)));
typedef unsigned short u16x8 __attribute__((ext_vector_type(8)));

__device__ __forceinline__ unsigned short f2bf(float f) {
    unsigned u = __builtin_bit_cast(unsigned, f);
    u += 0x7fffu + ((u >> 16) & 1u);   // RNE
    return (unsigned short)(u >> 16);
}

// ---------- prep: blocks 0..7 comb(b), 8..15 bfold(b), 16..143 fold ----------
__global__ __launch_bounds__(256) void k_prep(const float* __restrict__ Wb,
                                              const float* __restrict__ bb,
                                              const float* __restrict__ Wc,
                                              const float* __restrict__ bc,
                                              const float* __restrict__ We,
                                              const float* __restrict__ be,
                                              double* __restrict__ Wcomb,
                                              double* __restrict__ bcomb,
                                              unsigned short* __restrict__ Wfold,
                                              float* __restrict__ bfold) {
    __shared__ float clf[32][128];
    __shared__ float wbt[32][16];
    __shared__ double red[256];
    __shared__ float part[256];
    int blk = blockIdx.x, tid = threadIdx.x;

    if (blk < 8) {
        // Wcomb[b][k] = sum_h Wb[k][h] * We[b][h]  (fp64), bcomb[b]
        int b = blk, k = tid;
        const float4* wbr = (const float4*)(Wb + k * 256);
        const float4* wer = (const float4*)(We + b * 256);
        double a0 = 0.0, a1 = 0.0, a2 = 0.0, a3 = 0.0;
#pragma unroll 8
        for (int j = 0; j < 64; ++j) {
            float4 u = wbr[j], w = wer[j];
            a0 += (double)u.x * (double)w.x;
            a1 += (double)u.y * (double)w.y;
            a2 += (double)u.z * (double)w.z;
            a3 += (double)u.w * (double)w.w;
        }
        Wcomb[b * 256 + k] = (a0 + a1) + (a2 + a3);

        red[k] = (double)bb[k] * (double)We[b * 256 + k];
        __syncthreads();
        for (int s = 128; s; s >>= 1) {
            if (k < s) red[k] += red[k + s];
            __syncthreads();
        }
        if (k == 0) bcomb[b] = red[0] + (double)be[b];
        return;
    }

    if (blk < 16) {
        // b_fold[b][c] = bc[b][c] + sum_h bb[h]*Wc[b][h][c]; one branch/block, 2-way h split
        int b = blk - 8;
        int c = tid & 127, hg = tid >> 7;
        float a = 0.f;
#pragma unroll 16
        for (int h = 0; h < 128; ++h)
            a += bb[hg * 128 + h] * Wc[((b * 256 + hg * 128 + h)) * 128 + c];
        part[tid] = a;
        __syncthreads();
        if (tid < 128) bfold[b * 128 + tid] = part[tid] + part[tid + 128] + bc[b * 128 + tid];
        return;
    }

    // fold: Wfold[b][c][k] bf16  (= sum_h Wb[k][h]*Wc[b][h][c])
    int idx0 = blk - 16;
    int kg = idx0 & 15, b = idx0 >> 4;
    int c = tid & 127, kh = tid >> 7;

    float acc[8];
#pragma unroll
    for (int j = 0; j < 8; ++j) acc[j] = 0.f;

    for (int ht = 0; ht < 8; ++ht) {
#pragma unroll
        for (int j = 0; j < 16; ++j) {
            int idx = tid + j * 256;
            int hh = idx >> 7, cc = idx & 127;
            clf[hh][cc] = Wc[(b * 256 + ht * 32 + hh) * 128 + cc];
        }
#pragma unroll
        for (int j = 0; j < 2; ++j) {
            int idx = tid + j * 256;
            int hh = idx & 31, kk = idx >> 5;
            wbt[hh][kk] = Wb[(kg * 16 + kk) * 256 + ht * 32 + hh];
        }
        __syncthreads();
        for (int h = 0; h < 32; ++h) {
            float wc = clf[h][c];
            float4 w0 = *(const float4*)&wbt[h][kh * 8];
            float4 w1 = *(const float4*)&wbt[h][kh * 8 + 4];
            acc[0] += w0.x * wc; acc[1] += w0.y * wc;
            acc[2] += w0.z * wc; acc[3] += w0.w * wc;
            acc[4] += w1.x * wc; acc[5] += w1.y * wc;
            acc[6] += w1.z * wc; acc[7] += w1.w * wc;
        }
        __syncthreads();
    }
    unsigned short o8[8];
#pragma unroll
    for (int j = 0; j < 8; ++j) o8[j] = f2bf(acc[j]);
    u16x8 pk;
#pragma unroll
    for (int j = 0; j < 8; ++j) pk[j] = o8[j];
    int base = (b * 128 + c) * 256 + kg * 16 + kh * 8;
    *(u16x8*)&Wfold[base] = pk;
}

// ---------- fused: stage -> route (fp64) -> local bucket -> per-branch MFMA ----------
__global__ __launch_bounds__(256, 2) void k_main(const float* __restrict__ x,
                                                 const double* __restrict__ Wcomb,
                                                 const double* __restrict__ bcomb,
                                                 const unsigned short* __restrict__ Wfold,
                                                 const float* __restrict__ bfold,
                                                 float* __restrict__ out) {
    __shared__ float xs[ROWS * XST];          // 66560 B fp32 row cache
    __shared__ unsigned char list[8][ROWS];   // per-branch local row lists
    __shared__ int cnt[8];
    __shared__ unsigned char tasks[16];       // (b<<4)|group
    __shared__ int ntasks;

    const int tid = threadIdx.x;
    const int blk = blockIdx.x;
    const int wave = tid >> 6, lane = tid & 63;
    const int bl = lane & 7, kc = lane >> 3;   // lane = kc*8 + b
    const size_t rowbase = (size_t)blk * ROWS;

    if (tid < 8) cnt[tid] = 0;

    // Wcomb into VGPRs: w?[t] = Wcomb[bl][kc*4 + t*32 + {0,1,2,3}]  (interleaved k-chunks)
    double w0[8], w1[8], w2[8], w3[8];
    {
        const double* wb = Wcomb + bl * 256 + kc * 4;
#pragma unroll
        for (int t = 0; t < 8; ++t) {
            double2 p0 = *(const double2*)(wb + t * 32);
            double2 p1 = *(const double2*)(wb + t * 32 + 2);
            w0[t] = p0.x; w1[t] = p0.y; w2[t] = p1.x; w3[t] = p1.y;
        }
    }
    const double bco = bcomb[bl];

    // ---- phase A: stage 64 fp32 rows -> LDS (one wave-instruction per row slice)
#pragma unroll 4
    for (int it = 0; it < 16; ++it) {
        int idx = it * 256 + tid;
        int r = idx >> 6, gq = idx & 63;
        float4 v = *(const float4*)(x + (rowbase + r) * 256 + gq * 4);
        *(float4*)&xs[r * XST + gq * 4] = v;
    }
    __syncthreads();

    // ---- phase B: route 16 rows per wave; fp64; x broadcast from LDS (8-way), W in VGPRs
    for (int rr = 0; rr < 16; ++rr) {
        int r = wave * 16 + rr;
        const float* xr = xs + r * XST + kc * 4;
        double a0 = 0.0, a1 = 0.0, a2 = 0.0, a3 = 0.0;
#pragma unroll
        for (int t = 0; t < 8; ++t) {
            float4 v = *(const float4*)(xr + t * 32);
            a0 += (double)v.x * w0[t];
            a1 += (double)v.y * w1[t];
            a2 += (double)v.z * w2[t];
            a3 += (double)v.w * w3[t];
        }
        double e = (a0 + a2) + (a1 + a3);
        e += __shfl_xor(e, 8);     // reduce over kc
        e += __shfl_xor(e, 16);
        e += __shfl_xor(e, 32);
        e += bco;
        int bid = bl;
#pragma unroll
        for (int d = 4; d; d >>= 1) {   // argmin over b, first-index tie-break
            double o = __shfl_xor(e, d);
            int ob = __shfl_xor(bid, d);
            if (o < e || (o == e && ob < bid)) { e = o; bid = ob; }
        }
        if (lane == 0) {
            int p = atomicAdd(&cnt[bid], 1);
            list[bid][p] = (unsigned char)r;
        }
    }
    __syncthreads();

    if (tid == 0) {
        int nt = 0;
#pragma unroll
        for (int b = 0; b < 8; ++b) {
            int ng = (cnt[b] + 15) >> 4;
            for (int g = 0; g < ng; ++g) tasks[nt++] = (unsigned char)((b << 4) | g);
        }
        ntasks = nt;
    }
    __syncthreads();

    // ---- phase D: per-branch 16-row x 128-col MFMA tiles, one task per wave round-robin
    const int n16 = lane & 15, quad = lane >> 4;
    const int nt = ntasks;
    for (int t = wave; t < nt; t += 4) {
        int b = tasks[t] >> 4, g = tasks[t] & 15;
        int nb = cnt[b];
        int slot = g * 16 + n16;
        int arid = list[b][slot < nb ? slot : nb - 1];
        const float* ap = xs + arid * XST + quad * 8;

        bf16x8 Af[8];
#pragma unroll
        for (int kt = 0; kt < 8; ++kt) {
            float4 f0 = *(const float4*)(ap + kt * 32);
            float4 f1 = *(const float4*)(ap + kt * 32 + 4);
            u16x8 pk;
            pk[0] = f2bf(f0.x); pk[1] = f2bf(f0.y); pk[2] = f2bf(f0.z); pk[3] = f2bf(f0.w);
            pk[4] = f2bf(f1.x); pk[5] = f2bf(f1.y); pk[6] = f2bf(f1.z); pk[7] = f2bf(f1.w);
            Af[kt] = __builtin_bit_cast(bf16x8, pk);
        }

        const unsigned short* wb = Wfold + (size_t)(b * 128 + n16) * 256 + quad * 8;
        f32x4 acc[8];
#pragma unroll
        for (int ct = 0; ct < 8; ++ct) {
            float bias = bfold[b * 128 + ct * 16 + n16];
            acc[ct] = (f32x4){bias, bias, bias, bias};
        }
#pragma unroll
        for (int kt = 0; kt < 8; ++kt) {
            const unsigned short* wk = wb + kt * 32;
#pragma unroll
            for (int ct = 0; ct < 8; ++ct) {
                bf16x8 Bf = __builtin_bit_cast(bf16x8, *(const u16x8*)(wk + ct * 16 * 256));
                acc[ct] = __builtin_amdgcn_mfma_f32_16x16x32_bf16(Af[kt], Bf, acc[ct], 0, 0, 0);
            }
        }

        int srow[4];
#pragma unroll
        for (int reg = 0; reg < 4; ++reg) {
            int r16 = g * 16 + quad * 4 + reg;
            srow[reg] = r16 < nb ? (int)list[b][r16] : -1;
        }
#pragma unroll
        for (int ct = 0; ct < 8; ++ct) {
#pragma unroll
            for (int reg = 0; reg < 4; ++reg)
                if (srow[reg] >= 0)
                    out[(rowbase + srow[reg]) * 128 + ct * 16 + n16] = acc[ct][reg];
        }
    }
}

extern "C" void kernel_launch(void* const* d_in, const int* in_sizes, int n_in,
                              void* d_out, int out_size, void* d_ws, size_t ws_size,
                              hipStream_t stream) {
    const float* x  = (const float*)d_in[0];
    const float* Wb = (const float*)d_in[1];
    const float* bb = (const float*)d_in[2];
    const float* Wc = (const float*)d_in[3];
    const float* bc = (const float*)d_in[4];
    const float* We = (const float*)d_in[5];
    const float* be = (const float*)d_in[6];
    float* out = (float*)d_out;

    unsigned char* ws = (unsigned char*)d_ws;
    double* Wcomb = (double*)ws;                               //       0 : 16384 B
    double* bcomb = (double*)(ws + 16384);                     //   16384 : 64 B
    unsigned short* Wfold = (unsigned short*)(ws + 16448);     //   16448 : 524288 B
    float* bfold = (float*)(ws + 540736);                      //  540736 : 4096 B -> 544832 total

    hipLaunchKernelGGL(k_prep, dim3(144), dim3(256), 0, stream,
                       Wb, bb, Wc, bc, We, be, Wcomb, bcomb, Wfold, bfold);
    hipLaunchKernelGGL(k_main, dim3(NROWS / ROWS), dim3(256), 0, stream,
                       x, Wcomb, bcomb, Wfold, bfold, out);
}